// Round 7
// baseline (142.685 us; speedup 1.0000x reference)
//
#include <hip/hip_runtime.h>
#include <stdint.h>

// Problem constants
#define B_  1024
#define D_  512
#define K_  255
#define L_  256
#define C_  80

typedef __attribute__((ext_vector_type(8))) short bf16x8;
typedef __attribute__((ext_vector_type(4))) float f32x4;
typedef __attribute__((ext_vector_type(8))) short short8;

// async global->LDS, 16B per lane; dst must be wave-uniform base + lane*16.
#define GLD(gsrc, ldst) \
  __builtin_amdgcn_global_load_lds((const __attribute__((address_space(1))) void*)(gsrc), \
                                   (__attribute__((address_space(3))) void*)(ldst), 16, 0, 0)

__device__ __forceinline__ short cvt_bf16(float f) {
    unsigned u = __float_as_uint(f);
    u += 0x7FFFu + ((u >> 16) & 1u);
    return (short)(u >> 16);
}

// ---------------------------------------------------------------------------
// Kernel 1: convert W (20480x512) + x (1024x512) fp32->bf16, AND normalize
// ne rows -> bf16 neb (256 rows; row 255 zeroed).  Memory-bound (~66 MB),
// measured ~11 us ~= its 67 MB / 6.3 TB/s floor. Leave alone.
// ---------------------------------------------------------------------------
__global__ __launch_bounds__(256) void convert_kernel(const float* __restrict__ w,
                                                      const float* __restrict__ x,
                                                      const float* __restrict__ ne,
                                                      short* __restrict__ wb,
                                                      short* __restrict__ xb,
                                                      short* __restrict__ neb) {
    __shared__ float red[256];
    const int tid = threadIdx.x;
    if (blockIdx.x < 2048) {
        size_t i0 = (size_t)blockIdx.x * 256 + tid;
        const size_t stride = 2048u * 256u;
        for (size_t v = i0; v < 1310720u; v += stride) {
            float4 a = ((const float4*)w)[v * 2];
            float4 b = ((const float4*)w)[v * 2 + 1];
            short8 o;
            o[0] = cvt_bf16(a.x); o[1] = cvt_bf16(a.y); o[2] = cvt_bf16(a.z); o[3] = cvt_bf16(a.w);
            o[4] = cvt_bf16(b.x); o[5] = cvt_bf16(b.y); o[6] = cvt_bf16(b.z); o[7] = cvt_bf16(b.w);
            ((short8*)wb)[v] = o;
        }
        for (size_t v = i0; v < 65536u; v += stride) {
            float4 a = ((const float4*)x)[v * 2];
            float4 b = ((const float4*)x)[v * 2 + 1];
            short8 o;
            o[0] = cvt_bf16(a.x); o[1] = cvt_bf16(a.y); o[2] = cvt_bf16(a.z); o[3] = cvt_bf16(a.w);
            o[4] = cvt_bf16(b.x); o[5] = cvt_bf16(b.y); o[6] = cvt_bf16(b.z); o[7] = cvt_bf16(b.w);
            ((short8*)xb)[v] = o;
        }
    } else {
        const int row = blockIdx.x - 2048;  // 0..255
        if (row == 255) {
            ((unsigned*)(neb + 255 * 512))[tid] = 0u;  // pad row = zeros
            return;
        }
        const float2* nr = (const float2*)(ne + (size_t)row * 512);
        float2 a = nr[tid];
        red[tid] = a.x * a.x + a.y * a.y;
        __syncthreads();
        #pragma unroll
        for (int s = 128; s > 0; s >>= 1) {
            if (tid < s) red[tid] += red[tid + s];
            __syncthreads();
        }
        float inv = rsqrtf(red[0]);
        unsigned lo = (unsigned short)cvt_bf16(a.x * inv);
        unsigned hi = (unsigned short)cvt_bf16(a.y * inv);
        ((unsigned*)(neb + (size_t)row * 512))[tid] = lo | (hi << 16);
    }
}

// ---------------------------------------------------------------------------
// Kernel 2: sim GEMM: out1[b,k] = sigmoid(xb[b,:]·neb[k,:]). 64x64 tiles.
// ---------------------------------------------------------------------------
__global__ __launch_bounds__(256) void simgemm_kernel(const short* __restrict__ xb,
                                                      const short* __restrict__ neb,
                                                      float* __restrict__ out1) {
    __shared__ __align__(16) short Ald[512 * 8];
    __shared__ __align__(16) short Bld[512 * 8];
    const int tid = threadIdx.x;
    const int lane = tid & 63, wave = tid >> 6;
    const int q = lane >> 4, r = lane & 15;
    const int mt = blockIdx.x >> 2;
    const int nt = blockIdx.x & 3;

    f32x4 acc[4];
    #pragma unroll
    for (int nf = 0; nf < 4; ++nf) acc[nf] = (f32x4){0.f, 0.f, 0.f, 0.f};

    const bf16x8* Av = (const bf16x8*)Ald;
    const bf16x8* Bv = (const bf16x8*)Bld;

    for (int kb = 0; kb < 8; ++kb) {
        __syncthreads();
        #pragma unroll
        for (int j = 0; j < 2; ++j) {
            int ph = j * 256 + tid, rr = ph >> 3, g = (ph & 7) ^ (rr & 7);
            GLD(xb + ((size_t)(mt * 64 + rr) * D_ + kb * 64 + g * 8), Ald + ph * 8);
        }
        #pragma unroll
        for (int j = 0; j < 2; ++j) {
            int ph = j * 256 + tid, cc = ph >> 3, g = (ph & 7) ^ (cc & 7);
            GLD(neb + ((size_t)(nt * 64 + cc) * D_ + kb * 64 + g * 8), Bld + ph * 8);
        }
        __syncthreads();
        #pragma unroll
        for (int ks = 0; ks < 2; ++ks) {
            const int g = ks * 4 + q;
            int rl = wave * 16 + r;
            bf16x8 af = Av[rl * 8 + (g ^ (rl & 7))];
            #pragma unroll
            for (int nf = 0; nf < 4; ++nf) {
                int cl = nf * 16 + r;
                bf16x8 bfr = Bv[cl * 8 + (g ^ (cl & 7))];
                acc[nf] = __builtin_amdgcn_mfma_f32_16x16x32_bf16(af, bfr, acc[nf], 0, 0, 0);
            }
        }
    }
    #pragma unroll
    for (int nf = 0; nf < 4; ++nf) {
        int gcol = nt * 64 + nf * 16 + r;
        if (gcol < K_) {
            #pragma unroll
            for (int i = 0; i < 4; ++i) {
                int grow = mt * 64 + wave * 16 + q * 4 + i;
                out1[(size_t)grow * K_ + gcol] = 1.f / (1.f + __expf(-acc[nf][i]));
            }
        }
    }
}

// ---------------------------------------------------------------------------
// Kernel 3: leaf probabilities from out1 sigmoids. Block = batch row.
// Also zeroes out0 (runs before gemm/reduce; reduce atomicAdds into it).
// ---------------------------------------------------------------------------
__global__ __launch_bounds__(256) void leafprob_kernel(const float* __restrict__ out1,
                                                       float* __restrict__ p_ws,
                                                       float* __restrict__ out0) {
    __shared__ float ss[K_];
    const int b = blockIdx.x, t = threadIdx.x;
    if (t < K_) ss[t] = out1[(size_t)b * K_ + t];
    if (t < C_) out0[(size_t)b * C_ + t] = 0.f;   // zero-init for reduce atomics
    __syncthreads();
    float prob = 1.f;
    int node = 0;
    #pragma unroll
    for (int d = 0; d < 8; ++d) {
        int bit = (t >> (7 - d)) & 1;
        float s = ss[node];
        prob *= bit ? (1.f - s) : s;
        node = 2 * node + 1 + bit;
    }
    p_ws[(size_t)b * L_ + t] = prob;
}

// ---------------------------------------------------------------------------
// Kernel 4: main GEMM — OCCUPANCY round. Per-CU cycle ledger of r5
// (LDS-read 42K + MFMA 25K + fold 10K = 77K = runtime) shows the three
// pipes run fully SERIALIZED: 2 waves/SIMD barrier-locked gives no TLP to
// overlap them. All structural variants (r0/r4/r5/r6: 31.5-35.5 us) kept
// occupancy constant — that's why they were flat. m97 (same tile, K-step
// 64, ~3 blocks/CU) reaches 37% MfmaUtil on this exact shape.
// Change: shrink LDS to 28 KB/block so 4 blocks/CU co-reside (4 waves/SIMD):
//   - K-chunk 64: A 16 KB, single-leaf B 10 KB, p_t 2 KB.
//   - kb-outer(8) / li-inner(4) = 32 stages, same proven barrier rhythm.
//   - fold count doubles (kb 8 vs 4); offset by f32x4 packed folds
//     (v_pk_fma_f32) via transposed p_t[4][128]: 1 ds_read_b128 + 10
//     packed FMAs per (mf,li) fold.
// Register shape = r5's exact live set (dec 40 + outacc 40 + transients)
// -> compiles to VGPR=128 every round = the 16-wave/CU boundary. KEY
// check in counters: VGPR_Count must stay 128 and LDS_Block_Size 28672.
// Grid = mt(8) x lc(64) = 512 blocks (2 rounds of 4/CU); blockIdx%8 = lc%8
// keeps the 8 m-tiles sharing a W slab on one XCD (L2-resident).
// ---------------------------------------------------------------------------
__global__ __launch_bounds__(256, 2) void gemm_kernel(const short* __restrict__ xb,
                                                      const short* __restrict__ wb,
                                                      const float* __restrict__ p,
                                                      const float* __restrict__ lb,
                                                      float* __restrict__ partial) {
    __shared__ __align__(16) short Ald[1024 * 8];  // 128 rows x 8 granules = 16 KB
    __shared__ __align__(16) short Bld[640 * 8];   // 80 rows x 8 granules = 10 KB
    __shared__ __align__(16) float p_t[4][128];    // transposed p tile, 2 KB

    const int tid = threadIdx.x;
    const int lane = tid & 63, wave = tid >> 6;
    const int q = lane >> 4, r = lane & 15;
    const int wrow = wave * 32;
    const int lc = blockIdx.x & 63;   // 64 l-chunks of 4 leaves
    const int mt = blockIdx.x >> 6;   // 8 m-tiles of 128 rows

    if (tid < 128) {
        float4 pw = *(const float4*)(p + (size_t)(mt * 128 + tid) * L_ + lc * 4);
        p_t[0][tid] = pw.x; p_t[1][tid] = pw.y;
        p_t[2][tid] = pw.z; p_t[3][tid] = pw.w;
    }
    __syncthreads();  // p_t visible

    // outacc init = bias term: sum_li p_t[li][row] * lb[(lc*4+li)*80 + col]
    // (f32x4 across the i dimension: pf4 = p_t[li][base..base+3])
    f32x4 outacc[2][5];
    #pragma unroll
    for (int mf = 0; mf < 2; ++mf) {
        const int base = wrow + mf * 16 + q * 4;
        f32x4 pf[4];
        #pragma unroll
        for (int li = 0; li < 4; ++li) pf[li] = *(const f32x4*)&p_t[li][base];
        #pragma unroll
        for (int nf = 0; nf < 5; ++nf) {
            f32x4 s = pf[0] * lb[(size_t)(lc * 4 + 0) * C_ + nf * 16 + r];
            s += pf[1] * lb[(size_t)(lc * 4 + 1) * C_ + nf * 16 + r];
            s += pf[2] * lb[(size_t)(lc * 4 + 2) * C_ + nf * 16 + r];
            s += pf[3] * lb[(size_t)(lc * 4 + 3) * C_ + nf * 16 + r];
            outacc[mf][nf] = s;
        }
    }

    const bf16x8* Av = (const bf16x8*)Ald;
    const bf16x8* Bv = (const bf16x8*)Bld;
    const f32x4 z4 = {0.f, 0.f, 0.f, 0.f};

    for (int kb = 0; kb < 8; ++kb) {      // 8 K=64 chunks, A staged once each
        for (int li = 0; li < 4; ++li) {  // 4 leaves, B staged per (kb,li)
            __syncthreads();  // previous stage's readers done before overwrite
            if (li == 0) {
                // stage A: 1024 granules (128 rows x 8), 4 per thread
                #pragma unroll
                for (int j = 0; j < 4; ++j) {
                    int ph = j * 256 + tid;
                    int rr = ph >> 3;
                    int g  = (ph & 7) ^ (rr & 7);
                    GLD(xb + ((size_t)(mt * 128 + rr) * D_ + kb * 64 + g * 8), Ald + ph * 8);
                }
            }
            // stage B: 640 granules (80 rows x 8), 2.5 per thread
            #pragma unroll
            for (int j = 0; j < 2; ++j) {
                int ph = j * 256 + tid;
                int cc = ph >> 3;
                int g  = (ph & 7) ^ (cc & 7);
                GLD(wb + ((size_t)((lc * 4 + li) * C_ + cc) * D_ + kb * 64 + g * 8), Bld + ph * 8);
            }
            if (tid < 128) {
                int ph = 512 + tid;
                int cc = ph >> 3;
                int g  = (ph & 7) ^ (cc & 7);
                GLD(wb + ((size_t)((lc * 4 + li) * C_ + cc) * D_ + kb * 64 + g * 8), Bld + ph * 8);
            }
            __syncthreads();  // drains vmcnt(0): tiles complete

            f32x4 dec[2][5];
            #pragma unroll
            for (int ks = 0; ks < 2; ++ks) {  // 2 K=32 slices -> 20 MFMA/stage
                const int g = ks * 4 + q;
                bf16x8 af[2], bfr[5];
                #pragma unroll
                for (int mf = 0; mf < 2; ++mf) {
                    int rl = wrow + mf * 16 + r;
                    af[mf] = Av[rl * 8 + (g ^ (rl & 7))];
                }
                #pragma unroll
                for (int nf = 0; nf < 5; ++nf) {
                    int cl = nf * 16 + r;
                    bfr[nf] = Bv[cl * 8 + (g ^ (cl & 7))];
                }
                #pragma unroll
                for (int mf = 0; mf < 2; ++mf)
                    #pragma unroll
                    for (int nf = 0; nf < 5; ++nf)
                        dec[mf][nf] = __builtin_amdgcn_mfma_f32_16x16x32_bf16(
                            af[mf], bfr[nf], ks == 0 ? z4 : dec[mf][nf], 0, 0, 0);
            }

            // packed linear p-fold: pf4 covers the 4 acc rows of this (mf)
            #pragma unroll
            for (int mf = 0; mf < 2; ++mf) {
                f32x4 pf4 = *(const f32x4*)&p_t[li][wrow + mf * 16 + q * 4];
                #pragma unroll
                for (int nf = 0; nf < 5; ++nf)
                    outacc[mf][nf] += pf4 * dec[mf][nf];
            }
        }
    }

    // store partials: partial[lc][1024 rows][80 cols], this block owns 128 rows
    const size_t rbase = (size_t)lc * B_ + mt * 128;
    #pragma unroll
    for (int mf = 0; mf < 2; ++mf)
        #pragma unroll
        for (int nf = 0; nf < 5; ++nf)
            #pragma unroll
            for (int i = 0; i < 4; ++i) {
                int row = wrow + mf * 16 + q * 4 + i;
                int col = nf * 16 + r;
                partial[(rbase + row) * C_ + col] = outacc[mf][nf][i];
            }
}

// ---------------------------------------------------------------------------
// Kernel 5: reduce 64 lc partials -> out0 (1024x80).
// Grid 640 = 80 idx-chunks x 8 j-groups: each thread sums 8 slabs and
// atomicAdds (8-way contention only; out0 zeroed by leafprob).
// ---------------------------------------------------------------------------
__global__ __launch_bounds__(256) void reduce_kernel(const float* __restrict__ partial,
                                                     float* __restrict__ out0) {
    const int chunk = blockIdx.x >> 3;            // 0..79
    const int jg    = blockIdx.x & 7;             // 0..7
    const int idx   = chunk * 256 + threadIdx.x;  // float4 index < 20480
    const float4* p4 = (const float4*)partial;
    float4 s = {0.f, 0.f, 0.f, 0.f};
    #pragma unroll
    for (int j = 0; j < 8; ++j) {
        float4 v = p4[(size_t)(jg * 8 + j) * (B_ * C_ / 4) + idx];
        s.x += v.x; s.y += v.y; s.z += v.z; s.w += v.w;
    }
    float* o = out0 + (size_t)idx * 4;
    atomicAdd(o + 0, s.x);
    atomicAdd(o + 1, s.y);
    atomicAdd(o + 2, s.z);
    atomicAdd(o + 3, s.w);
}

// ---------------------------------------------------------------------------
extern "C" void kernel_launch(void* const* d_in, const int* in_sizes, int n_in,
                              void* d_out, int out_size, void* d_ws, size_t ws_size,
                              hipStream_t stream) {
    const float* x  = (const float*)d_in[0];  // 1024x512
    const float* ne = (const float*)d_in[1];  // 255x512
    const float* lW = (const float*)d_in[2];  // 20480x512
    const float* lb = (const float*)d_in[3];  // 20480
    // d_in[4] res_path: deterministic structure, traversed directly

    float* out0 = (float*)d_out;            // 1024x80
    float* out1 = out0 + (size_t)B_ * C_;   // 1024x255

    char* ws = (char*)d_ws;
    short* xb      = (short*)ws;                             // 1 MB
    short* neb     = (short*)(ws + (1u << 20));              // 256 KB
    float* p_ws    = (float*)(ws + (1u << 20) + (1u << 18)); // 1 MB
    short* wb      = (short*)(ws + (9u << 18));              // 20 MB @ 2.25 MB
    float* partial = (float*)(ws + (24u << 20));             // 21 MB (64x1024x80)

    convert_kernel<<<2304, 256, 0, stream>>>(lW, x, ne, wb, xb, neb);
    simgemm_kernel<<<64, 256, 0, stream>>>(xb, neb, out1);
    leafprob_kernel<<<B_, 256, 0, stream>>>(out1, p_ws, out0);
    gemm_kernel<<<512, 256, 0, stream>>>(xb, wb, p_ws, lb, partial);
    reduce_kernel<<<640, 256, 0, stream>>>(partial, out0);
}